// Round 11
// baseline (399.787 us; speedup 1.0000x reference)
//
#include <hip/hip_runtime.h>
#include <hip/hip_bf16.h>

typedef unsigned short u16;
typedef unsigned int u32;
typedef __attribute__((ext_vector_type(8))) short short8;   // 8 x bf16 frag
typedef __attribute__((ext_vector_type(4))) short short4v;  // 4 x bf16 pack
typedef __attribute__((ext_vector_type(16))) float f32x16;  // 32x32 acc

#define MFMA32 __builtin_amdgcn_mfma_f32_32x32x16_bf16

#define NSEQ 4096
#define CD 256
// (1/sqrt(256)) * log2(e) = 0.0625 * 1.4426950408889634  -- EXACT.
#define CF 0.09016844005556021f

__device__ __forceinline__ u16 f2bf(float f) {
  u32 u = __float_as_uint(f);
  u += 0x7fffu + ((u >> 16) & 1u);  // RNE
  return (u16)(u >> 16);
}
__device__ __forceinline__ float bf2f(short s) {
  return __uint_as_float(((u32)(u16)s) << 16);
}
// HW packed f32x2 -> bf16x2 (gfx950 v_cvt_pk_bf16_f32), RNE
__device__ __forceinline__ u32 pk2bf(float a, float b) {
  union {
    __hip_bfloat162 h;
    u32 u;
  } cv;
  cv.h = __float22bfloat162_rn(make_float2(a, b));
  return cv.u;
}
// async global -> LDS DMA, 16B per lane; LDS dest = wave-uniform base + lane*16
__device__ __forceinline__ void async16(const void* g, void* l) {
  __builtin_amdgcn_global_load_lds(
      (const __attribute__((address_space(1))) u32*)g,
      (__attribute__((address_space(3))) u32*)l, 16, 0, 0);
}

// ---------------------------------------------------------------------------
// transpose-cast x: (b, 256, 4096) f32 -> x_t (b, 4096, 256) bf16
// + folded weight cast (1024 blocks x 256 weight elems)
// ---------------------------------------------------------------------------
__global__ __launch_bounds__(256) void xpose_cast(const float* __restrict__ x,
                                                  u16* __restrict__ x_t,
                                                  const float* __restrict__ qkv_w,
                                                  const float* __restrict__ out_w,
                                                  u16* __restrict__ wq,
                                                  u16* __restrict__ wo) {
  __shared__ float tile[64][65];
  const int t = threadIdx.x;
  {
    int lin = blockIdx.x + 64 * (blockIdx.y + 4 * blockIdx.z);
    int widx = lin * 256 + t;
    if (widx < 768 * CD)
      wq[widx] = f2bf(qkv_w[widx]);
    else
      wo[widx - 768 * CD] = f2bf(out_w[widx - 768 * CD]);
  }
  const int b = blockIdx.z;
  const int n0 = blockIdx.x * 64, c0 = blockIdx.y * 64;
  const float* xb = x + (size_t)b * CD * NSEQ;
  const int cr = t >> 4, nc4 = (t & 15) * 4;
#pragma unroll
  for (int i = 0; i < 4; ++i) {
    int c = cr + 16 * i;
    float4 v = *(const float4*)(xb + (size_t)(c0 + c) * NSEQ + n0 + nc4);
    tile[c][nc4 + 0] = v.x;
    tile[c][nc4 + 1] = v.y;
    tile[c][nc4 + 2] = v.z;
    tile[c][nc4 + 3] = v.w;
  }
  __syncthreads();
  const int n = t & 63, cc = (t >> 6) * 16;
  u16* dst = x_t + (size_t)b * NSEQ * CD + (size_t)(n0 + n) * CD + c0 + cc;
#pragma unroll
  for (int j = 0; j < 4; ++j) {
    short4v pv;
#pragma unroll
    for (int r = 0; r < 4; ++r) pv[r] = (short)f2bf(tile[cc + 4 * j + r][n]);
    *(short4v*)(dst + 4 * j) = pv;
  }
}

// ---------------------------------------------------------------------------
// QKV projection, 128x128 tile, 512 threads (8 waves), 32x32x16 MFMA.
// (unchanged from R10)
// ---------------------------------------------------------------------------
__global__ __launch_bounds__(512, 1) void qkv_gemm3(
    const u16* __restrict__ wq, const float* __restrict__ qkv_b,
    const u16* __restrict__ x_t, u16* __restrict__ q_t, u16* __restrict__ k_t,
    u16* __restrict__ v_) {
  __shared__ u16 __align__(16) Wls[128 * 256];
  __shared__ u16 __align__(16) Bls[128 * 256];
  const int t = threadIdx.x, w = t >> 6, lane = t & 63;
  const int l31 = lane & 31, l5 = lane >> 5;
  const int os = w & 3, nh = w >> 2;
  const int n0 = blockIdx.x * 128, o0 = blockIdx.y * 128, b = blockIdx.z;
  const u16* Xb = x_t + (size_t)b * NSEQ * CD;
#pragma unroll
  for (int j = 0; j < 8; ++j) {
    int r = w * 16 + j * 2 + l5;
    async16(wq + (size_t)(o0 + r) * CD + ((l31 ^ (r & 7)) * 8),
            Wls + (w * 16 + j * 2) * 256);
    async16(Xb + (size_t)(n0 + r) * CD + ((l31 ^ (r & 7)) * 8),
            Bls + (w * 16 + j * 2) * 256);
  }
  __builtin_amdgcn_s_waitcnt(0);
  __syncthreads();
  f32x16 acc0, acc1;
#pragma unroll
  for (int i = 0; i < 16; ++i) {
    acc0[i] = 0.f;
    acc1[i] = 0.f;
  }
  const int ra = os * 32 + l31;
  const int rb0 = nh * 64 + l31, rb1 = rb0 + 32;
#pragma unroll
  for (int kc = 0; kc < 16; ++kc) {
    short8 a = *(const short8*)(Wls + ra * 256 + (((kc * 2 + l5) ^ (ra & 7)) * 8));
    short8 b0 = *(const short8*)(Bls + rb0 * 256 + (((kc * 2 + l5) ^ (rb0 & 7)) * 8));
    short8 b1 = *(const short8*)(Bls + rb1 * 256 + (((kc * 2 + l5) ^ (rb1 & 7)) * 8));
    acc0 = MFMA32(a, b0, acc0, 0, 0, 0);
    acc1 = MFMA32(a, b1, acc1, 0, 0, 0);
  }
  const int otype = blockIdx.y >> 1;  // 0=Q 1=K 2=V
  const int obase = o0 + os * 32;
#pragma unroll
  for (int na = 0; na < 2; ++na) {
    f32x16& acc = na ? acc1 : acc0;
    const int n_g = n0 + nh * 64 + na * 32 + l31;
    if (otype < 2) {
      u16* dst = (otype == 0 ? q_t : k_t) + (size_t)b * NSEQ * CD +
                 (size_t)n_g * CD + (obase - otype * 256);
#pragma unroll
      for (int g = 0; g < 4; ++g) {
        float4 bv = *(const float4*)(qkv_b + obase + g * 8 + l5 * 4);
        const float* bp = (const float*)&bv;
        short4v pk;
#pragma unroll
        for (int r = 0; r < 4; ++r) pk[r] = (short)f2bf(acc[g * 4 + r] + bp[r]);
        *(short4v*)(dst + g * 8 + l5 * 4) = pk;
      }
    } else {
      u16* dst = v_ + (size_t)b * CD * NSEQ;
#pragma unroll
      for (int g = 0; g < 4; ++g) {
        float4 bv = *(const float4*)(qkv_b + obase + g * 8 + l5 * 4);
        const float* bp = (const float*)&bv;
#pragma unroll
        for (int r = 0; r < 4; ++r) {
          int c = obase - 512 + g * 8 + l5 * 4 + r;
          dst[(size_t)c * NSEQ + n_g] = f2bf(acc[g * 4 + r] + bp[r]);
        }
      }
    }
  }
}

// ---------------------------------------------------------------------------
// Flash attention v9: 3 blocks/CU. 256-thread blocks (4 waves), 32-key tiles,
// LDS 48 KB: K SINGLE-buffered (16K) + V DOUBLE-buffered (32K).
// Key-split 8 -> grid 1024 (4b x 8q x 32 mblk), 16 tiles/block.
// Per tile: TOP drain barrier -> S (K reads) -> softmax -> B2 (all waves done
// with K) -> issue K(t+1) + V(t+1 -> other buf) DMAs -> PV (V[cur]).
// V(t+1) WAR-safe: PV(t-1) reads of that buffer finished before TOP(t).
// Wave = m-strip (32 m), fully independent online-softmax stream (flash7/8
// math: in-wave softmax, 4-shfl P transform, 8 full-c accumulators).
// ---------------------------------------------------------------------------
__global__ __launch_bounds__(256, 3) void flash9(const u16* __restrict__ q_t,
                                                 const u16* __restrict__ k_t,
                                                 const u16* __restrict__ v_,
                                                 u16* __restrict__ opart,
                                                 float2* __restrict__ ml) {
  __shared__ u16 __align__(16) Kls[32 * 256];     // single buffer [n][c] swz
  __shared__ u16 __align__(16) Vls[2][128 * 64];  // dbuf [c-pair rows] swz

  const int t = threadIdx.x, w = t >> 6, lane = t & 63;
  const int l31 = lane & 31, l5 = lane >> 5;

  // XCD swizzle: xcd owns (b, 4 key-eighths) -> ~4MB K/V/Q in its L2.
  const int linear = blockIdx.x;
  const int xcd = linear & 7, slot = linear >> 3;  // slot in [0,128)
  const int b = xcd >> 1;
  const int q = (xcd & 1) * 4 + (slot >> 5);  // key-eighth 0..7
  const int mblk = slot & 31;
  const int m0 = mblk * 128;
  const int nbase = q * 512;
  const int TILES = 16;  // 512 keys / 32

  const u16* Qb = q_t + (size_t)b * NSEQ * CD;
  const u16* Kb = k_t + (size_t)b * NSEQ * CD;
  const u16* Vb = v_ + (size_t)b * CD * NSEQ;

  const int mrow = m0 + w * 32 + l31;  // global query index

  // Q fragments in registers (B-operand for S), K=256
  short8 qf[16];
#pragma unroll
  for (int kc = 0; kc < 16; ++kc)
    qf[kc] = *(const short8*)(Qb + (size_t)mrow * CD + kc * 16 + l5 * 8);

  // --- per-lane staging address constants (same pattern as flash8) ---
  const u16* ksrc[4];
#pragma unroll
  for (int j = 0; j < 4; ++j) {
    int r = w * 8 + j * 2 + l5;
    ksrc[j] = Kb + (size_t)r * CD + ((l31 ^ (r & 7)) * 8);
  }
  const u16* vsrc[4];
#pragma unroll
  for (int j = 0; j < 4; ++j) {
    int c2 = w * 32 + j * 8 + (lane >> 3);
    int chl = (lane & 7) ^ (c2 & 7);
    int c = (c2 << 1) | (chl >> 2);
    vsrc[j] = Vb + (size_t)c * NSEQ + (chl & 3) * 8;
  }

  // stage tile 0 (K -> Kls, V -> Vls[0])
#pragma unroll
  for (int j = 0; j < 4; ++j) {
    async16(ksrc[j] + (size_t)nbase * CD, Kls + (w * 8 + j * 2) * 256);
    async16(vsrc[j] + nbase, &Vls[0][(w * 32 + j * 8) * 64]);
  }

  float mst = -3.0e38f, lst = 0.f;
  f32x16 oa[8];  // O[c = ct*32 + rowmap][m = mrow]
#pragma unroll
  for (int i = 0; i < 8; ++i)
#pragma unroll
    for (int r = 0; r < 16; ++r) oa[i][r] = 0.f;

  for (int tt = 0; tt < TILES; ++tt) {
    const int cur = tt & 1;
    // TOP drain: tile tt's K and V DMAs landed; all waves past tile tt-1
    __builtin_amdgcn_s_waitcnt(0);
    __syncthreads();
    // ---- S = K . Q^T : 32n x own 32m, K=256 (reads single K buffer) ----
    f32x16 sa;
#pragma unroll
    for (int i = 0; i < 16; ++i) sa[i] = 0.f;
#pragma unroll
    for (int kc = 0; kc < 16; ++kc) {
      short8 a =
          *(const short8*)(Kls + l31 * 256 + (((kc * 2 + l5) ^ (l31 & 7)) * 8));
      sa = MFMA32(a, qf[kc], sa, 0, 0, 0);
    }
    // ---- softmax, fully in-wave (m = l31; l5 halves merge via xor32) ----
    float rm = sa[0];
#pragma unroll
    for (int i = 1; i < 16; ++i) rm = fmaxf(rm, sa[i]);
    rm = fmaxf(rm, __shfl_xor(rm, 32));
    float mnew = fmaxf(mst, rm * CF);
    float al = exp2f(mst - mnew);
    mst = mnew;
    u32 d[4][2];
    float ls = 0.f;
#pragma unroll
    for (int gg = 0; gg < 4; ++gg) {
      float p0 = exp2f(sa[gg * 4 + 0] * CF - mnew);
      float p1 = exp2f(sa[gg * 4 + 1] * CF - mnew);
      float p2 = exp2f(sa[gg * 4 + 2] * CF - mnew);
      float p3 = exp2f(sa[gg * 4 + 3] * CF - mnew);
      ls += (p0 + p1) + (p2 + p3);
      d[gg][0] = pk2bf(p0, p1);
      d[gg][1] = pk2bf(p2, p3);
    }
    ls += __shfl_xor(ls, 32);
    lst = lst * al + ls;
    if (__ballot(al != 1.0f)) {
#pragma unroll
      for (int i = 0; i < 8; ++i)
#pragma unroll
        for (int r = 0; r < 16; ++r) oa[i][r] *= al;
    }
    // ---- build P B-frags via l5-partner exchange (4 shfl_xor) ----
    short8 pf[2];
#pragma unroll
    for (int f = 0; f < 2; ++f) {
      const int g0 = f * 2;
      u32 sx0 = l5 ? d[g0][0] : d[g0 + 1][0];
      u32 sx1 = l5 ? d[g0][1] : d[g0 + 1][1];
      u32 e0 = (u32)__shfl_xor((int)sx0, 32);
      u32 e1 = (u32)__shfl_xor((int)sx1, 32);
      union {
        u32 u[4];
        short8 s8;
      } cv;
      cv.u[0] = l5 ? e0 : d[g0][0];
      cv.u[1] = l5 ? e1 : d[g0][1];
      cv.u[2] = l5 ? d[g0 + 1][0] : e0;
      cv.u[3] = l5 ? d[g0 + 1][1] : e1;
      pf[f] = cv.s8;
    }
    // ---- B2: all waves finished S reads of Kls -> safe to restage K ----
    __syncthreads();
    if (tt + 1 < TILES) {
      const int n0 = nbase + (tt + 1) * 32;
#pragma unroll
      for (int j = 0; j < 4; ++j) {
        async16(ksrc[j] + (size_t)n0 * CD, Kls + (w * 8 + j * 2) * 256);
        async16(vsrc[j] + n0, &Vls[cur ^ 1][(w * 32 + j * 8) * 64]);
      }
    }
    // ---- O += V . P : full 256 c (8 subtiles) x 32 keys (reads Vls[cur]) --
#pragma unroll
    for (int f = 0; f < 2; ++f) {
#pragma unroll
      for (int ct = 0; ct < 8; ++ct) {
        int c2r = ct * 16 + (l31 >> 1);
        int chl = ((l31 & 1) << 2) | (f * 2 + l5);
        short8 vf =
            *(const short8*)(&Vls[cur][c2r * 64 + ((chl ^ (c2r & 7)) * 8)]);
        oa[ct] = MFMA32(vf, pf[f], oa[ct], 0, 0, 0);
      }
    }
  }

  // ---- finalize: per-stream normalized O -> bf16; (m,l) for merge ----
  float inv = 1.0f / lst;
  u16* dst = opart + ((size_t)(q * 4 + b) * NSEQ + mrow) * CD;
#pragma unroll
  for (int ct = 0; ct < 8; ++ct)
#pragma unroll
    for (int gg = 0; gg < 4; ++gg) {
      short4v pk;
#pragma unroll
      for (int r = 0; r < 4; ++r) pk[r] = (short)f2bf(oa[ct][gg * 4 + r] * inv);
      *(short4v*)(dst + ct * 32 + gg * 8 + l5 * 4) = pk;
    }
  if (lane < 32)
    ml[(size_t)(q * 4 + b) * NSEQ + mrow] = make_float2(mst, lst);
}

// ---------------------------------------------------------------------------
// out projection + 8-stream split-key merge folded into B-tile staging.
// 128n x 128o tiles, 512 threads. grid (32, 2, 4).
// ---------------------------------------------------------------------------
__global__ __launch_bounds__(512, 1) void out_gemm7(
    const u16* __restrict__ wo, const float* __restrict__ out_b,
    const u16* __restrict__ opart, const float2* __restrict__ ml,
    float* __restrict__ out) {
  __shared__ u16 __align__(16) Wls[128 * 256];
  __shared__ u16 __align__(16) Bls[128 * 256];
  const int t = threadIdx.x, w = t >> 6, lane = t & 63;
  const int l31 = lane & 31, l5 = lane >> 5;
  const int os = w & 3, nh = w >> 2;
  const int n0 = blockIdx.x * 128, o0 = blockIdx.y * 128, b = blockIdx.z;
#pragma unroll
  for (int j = 0; j < 8; ++j) {
    int r = w * 16 + j * 2 + l5;
    async16(wo + (size_t)(o0 + r) * CD + ((l31 ^ (r & 7)) * 8),
            Wls + (w * 16 + j * 2) * 256);
  }
#pragma unroll
  for (int i = 0; i < 8; ++i) {
    int idx = i * 512 + t;
    int r = idx >> 5, p = idx & 31;
    int n = n0 + r;
    float2 st[8];
#pragma unroll
    for (int qq = 0; qq < 8; ++qq) st[qq] = ml[(size_t)(qq * 4 + b) * NSEQ + n];
    float M = st[0].x;
#pragma unroll
    for (int qq = 1; qq < 8; ++qq) M = fmaxf(M, st[qq].x);
    float wt[8], tot = 0.f;
#pragma unroll
    for (int qq = 0; qq < 8; ++qq) {
      wt[qq] = st[qq].y * exp2f(st[qq].x - M);
      tot += wt[qq];
    }
    float inv = 1.0f / tot;
    float acc[8] = {};
#pragma unroll
    for (int qq = 0; qq < 8; ++qq) {
      float wq_ = wt[qq] * inv;
      short8 xq =
          *(const short8*)(opart + ((size_t)(qq * 4 + b) * NSEQ + n) * CD + p * 8);
#pragma unroll
      for (int e = 0; e < 8; ++e) acc[e] += wq_ * bf2f(xq[e]);
    }
    short8 om;
#pragma unroll
    for (int e = 0; e < 8; ++e) om[e] = (short)f2bf(acc[e]);
    *(short8*)(Bls + r * 256 + ((p ^ (r & 7)) * 8)) = om;
  }
  __builtin_amdgcn_s_waitcnt(0);
  __syncthreads();
  f32x16 acc0, acc1;
#pragma unroll
  for (int i = 0; i < 16; ++i) {
    acc0[i] = 0.f;
    acc1[i] = 0.f;
  }
  const int ra = os * 32 + l31;
  const int rb0 = nh * 64 + l31, rb1 = rb0 + 32;
#pragma unroll
  for (int kc = 0; kc < 16; ++kc) {
    short8 a = *(const short8*)(Wls + ra * 256 + (((kc * 2 + l5) ^ (ra & 7)) * 8));
    short8 b0 = *(const short8*)(Bls + rb0 * 256 + (((kc * 2 + l5) ^ (rb0 & 7)) * 8));
    short8 b1 = *(const short8*)(Bls + rb1 * 256 + (((kc * 2 + l5) ^ (rb1 & 7)) * 8));
    acc0 = MFMA32(a, b0, acc0, 0, 0, 0);
    acc1 = MFMA32(a, b1, acc1, 0, 0, 0);
  }
  const int obase = o0 + os * 32;
#pragma unroll
  for (int na = 0; na < 2; ++na) {
    f32x16& acc = na ? acc1 : acc0;
    const int n_g = n0 + nh * 64 + na * 32 + l31;
#pragma unroll
    for (int g = 0; g < 4; ++g) {
      float4 bv = *(const float4*)(out_b + obase + g * 8 + l5 * 4);
      const float* bp = (const float*)&bv;
#pragma unroll
      for (int r = 0; r < 4; ++r) {
        int o = obase + g * 8 + l5 * 4 + r;
        out[((size_t)b * CD + o) * NSEQ + n_g] = acc[g * 4 + r] + bp[r];
      }
    }
  }
}

// ---------------------------------------------------------------------------
extern "C" void kernel_launch(void* const* d_in, const int* in_sizes, int n_in,
                              void* d_out, int out_size, void* d_ws,
                              size_t ws_size, hipStream_t stream) {
  const float* x = (const float*)d_in[0];
  const float* qkv_w = (const float*)d_in[1];
  const float* qkv_b = (const float*)d_in[2];
  const float* out_w = (const float*)d_in[3];
  const float* out_b = (const float*)d_in[4];
  float* out = (float*)d_out;

  const size_t SZ = (size_t)4 * NSEQ * CD;  // elems per (b,4096,256) bf16
  u16* q_t = (u16*)d_ws;
  u16* k_t = q_t + SZ;
  u16* v_ = k_t + SZ;
  u16* opart = v_ + SZ;  // 8 key-stream eighths, 8*SZ
  // x_t aliases opart's first stream: x_t is dead (qkv_gemm3 done) before
  // flash9 writes any of opart -- stream-ordered, safe.
  u16* x_t = opart;
  u16* wq = opart + 8 * SZ;              // 768*256
  u16* wo = wq + 768 * CD;               // 256*256
  float2* ml = (float2*)(wo + CD * CD);  // 8*4*4096 float2

  xpose_cast<<<dim3(64, 4, 4), dim3(256), 0, stream>>>(x, x_t, qkv_w, out_w,
                                                       wq, wo);
  qkv_gemm3<<<dim3(32, 6, 4), dim3(512), 0, stream>>>(wq, qkv_b, x_t, q_t, k_t,
                                                      v_);
  flash9<<<dim3(1024), dim3(256), 0, stream>>>(q_t, k_t, v_, opart, ml);
  out_gemm7<<<dim3(32, 2, 4), dim3(512), 0, stream>>>(wo, out_b, opart, ml,
                                                      out);
}